// Round 12
// baseline (207.710 us; speedup 1.0000x reference)
//
#include <hip/hip_runtime.h>
#include <stdint.h>

// Problem: B=2, S=2048, D=1024, H=16, HD=64.
// Reference dtype fp32; harness may deliver fp32 OR bf16. Runtime-detected.
#define Bb 2
#define Ss 2048
#define Dd 1024
#define Hh 16
#define HD 64
#define Mtot 4096  // B*S

typedef __bf16 bf16x8 __attribute__((ext_vector_type(8)));
typedef float f32x4 __attribute__((ext_vector_type(4)));
typedef float f32x16 __attribute__((ext_vector_type(16)));
typedef unsigned short ushort_t;

#if __has_builtin(__builtin_amdgcn_exp2f)
#define EXP2(x) __builtin_amdgcn_exp2f(x)   // single v_exp_f32
#else
#define EXP2(x) __expf((x) * 0.6931472f)
#endif

__device__ __forceinline__ float bf2f(ushort_t u) {
    union { uint32_t i; float f; } v;
    v.i = ((uint32_t)u) << 16;
    return v.f;
}

__device__ __forceinline__ ushort_t f2bf(float f) {
    union { float f; uint32_t i; } v;
    v.f = f;
    uint32_t u = v.i;
    u += 0x7FFFu + ((u >> 16) & 1u);  // round-to-nearest-even
    return (ushort_t)(u >> 16);
}

// v_cvt_pk_bf16_f32: dst.lo16 = bf16(lo), dst.hi16 = bf16(hi), RNE.
__device__ __forceinline__ uint32_t cvtpk_bf16(float lo, float hi) {
    uint32_t r;
    asm("v_cvt_pk_bf16_f32 %0, %1, %2" : "=v"(r) : "v"(lo), "v"(hi));
    return r;
}

__device__ __forceinline__ float load_in(const void* p, size_t i, int isf32) {
    if (isf32) return ((const float*)p)[i];
    return bf2f(((const ushort_t*)p)[i]);
}

// async global->LDS, 16B per lane; LDS dest = wave-uniform base + lane*16 (HW)
__device__ __forceinline__ void gload_lds16(const void* g, void* l) {
    __builtin_amdgcn_global_load_lds(
        (const __attribute__((address_space(1))) void*)g,
        (__attribute__((address_space(3))) void*)l, 16, 0, 0);
}

// ---------------------------------------------------------------------------
// Kernel P: fused prep (R11-exact). Blocks 0..1023: vectorized convert of
// X/mask/biases. Blocks 1024..2047: vectorized 64x64 transpose W -> wt.
// ---------------------------------------------------------------------------
#define NVEC 525568ull  // 524288 (X) + 512 (mask) + 768 (6x1024 biases)
__global__ __launch_bounds__(256) void prep_k(
    const void* X, const void* mask, const void* bq, const void* bk,
    const void* bv, const void* bo, const void* g, const void* be,
    const void* Wq, const void* Wk, const void* Wv, const void* Wo,
    int* __restrict__ flag, ushort_t* __restrict__ cX,
    ushort_t* __restrict__ cMask, ushort_t* __restrict__ cB,
    ushort_t* __restrict__ wt) {
    __shared__ int sflag;
    __shared__ __align__(16) ushort_t ttile[64][72];  // 9216B, pitch 144B
    const int tid = threadIdx.x;
    {
        const int lane = tid & 63;
        if (tid < 64) {
            const ushort_t* Xu = (const ushort_t*)X;
            int local = 0;
            for (int i = lane; i < 2048; i += 64) {
                int e = (Xu[i] >> 7) & 0xFF;
                local += (e >= 0x90);
            }
            for (int off = 1; off < 64; off <<= 1) local += __shfl_xor(local, off);
            if (lane == 0) sflag = (local >= 4) ? 1 : 0;
        }
    }
    __syncthreads();
    const int f = sflag;
    if (blockIdx.x == 0 && tid == 0) *flag = f;

    if (blockIdx.x < 1024) {
        const size_t stride = 1024ull * 256ull;
        for (size_t t = (size_t)blockIdx.x * 256 + tid; t < NVEC; t += stride) {
            const void* src;
            ushort_t* dst;
            size_t v;
            if (t < 524288ull) {
                src = X; dst = cX; v = t;
            } else if (t < 524800ull) {
                src = mask; dst = cMask; v = t - 524288ull;
            } else {
                size_t j = t - 524800ull;        // 0..767, 128 vecs / segment
                int w = (int)(j >> 7);
                src = (w == 0) ? bq : (w == 1) ? bk : (w == 2) ? bv
                    : (w == 3) ? bo : (w == 4) ? g : be;
                dst = cB + w * 1024;
                v = j & 127;
            }
            if (f) {
                const float4* s4 = (const float4*)src;
                float4 a = s4[v * 2], b = s4[v * 2 + 1];
                union { ushort_t u[8]; uint4 q; } pk;
                pk.u[0] = f2bf(a.x); pk.u[1] = f2bf(a.y);
                pk.u[2] = f2bf(a.z); pk.u[3] = f2bf(a.w);
                pk.u[4] = f2bf(b.x); pk.u[5] = f2bf(b.y);
                pk.u[6] = f2bf(b.z); pk.u[7] = f2bf(b.w);
                ((uint4*)dst)[v] = pk.q;
            } else {
                ((uint4*)dst)[v] = ((const uint4*)src)[v];
            }
        }
    } else {
        // ---- vectorized 64x64 transpose: T[n][k] = W[k][n] ----
        int id2 = blockIdx.x - 1024;     // 0..1023
        int z = id2 >> 8;                // matrix 0..3
        int rem = id2 & 255;
        int bx = rem & 15, by = rem >> 4;  // col-tile, row-tile
        const void* W = (z == 0) ? Wq : (z == 1) ? Wk : (z == 2) ? Wv : Wo;
        ushort_t* T = wt + (size_t)z * Dd * Dd;
        const int y0 = by * 64;  // W row origin (k)
        const int x0 = bx * 64;  // W col origin (n)

        // write phase: thread t -> row r = t>>2, x-chunk cq = t&3 (16 elems)
        {
            const int r = tid >> 2, cq = tid & 3;
            const int cq2 = cq ^ ((r >> 4) & 3);  // y-chunk XOR swizzle
            union { ushort_t u[16]; uint4 q[2]; } pk;
            if (f) {
                const float* Wf = (const float*)W;
                const float4* src = (const float4*)&Wf[(size_t)(y0 + r) * Dd + x0 + cq * 16];
#pragma unroll
                for (int j = 0; j < 4; j++) {
                    float4 a = src[j];
                    pk.u[j * 4 + 0] = f2bf(a.x);
                    pk.u[j * 4 + 1] = f2bf(a.y);
                    pk.u[j * 4 + 2] = f2bf(a.z);
                    pk.u[j * 4 + 3] = f2bf(a.w);
                }
            } else {
                const ushort_t* Wu = (const ushort_t*)W;
                const uint4* src = (const uint4*)&Wu[(size_t)(y0 + r) * Dd + x0 + cq * 16];
                pk.q[0] = src[0];
                pk.q[1] = src[1];
            }
            *(uint4*)&ttile[r][cq2 * 16] = pk.q[0];
            *(uint4*)&ttile[r][cq2 * 16 + 8] = pk.q[1];
        }
        __syncthreads();
        // read phase: thread t -> output row x = t>>2 (n), y-chunk yq = t&3
        {
            const int x = tid >> 2, yq = tid & 3;
            const int xs = x ^ (yq << 4);  // same swizzle: (y>>4)&3 == yq here
            union { ushort_t u[16]; uint4 q[2]; } pk;
#pragma unroll
            for (int i = 0; i < 16; i++) pk.u[i] = ttile[yq * 16 + i][xs];
            uint4* dst = (uint4*)&T[(size_t)(x0 + x) * Dd + y0 + yq * 16];
            dst[0] = pk.q[0];
            dst[1] = pk.q[1];
        }
    }
}

// ---------------------------------------------------------------------------
// Kernel 1: fused QKV projection (R4 main loop; R12 adds T1 XCD swizzle:
// per-z nwg=256, swz=(lin&7)*32+(lin>>3) is bijective (256%8==0) -> each
// XCD keeps a 1MB X row-band L2-resident across its column sweep).
// grid=(N/128, M/128, 3), block=256 (4 waves), double-buffered
// global_load_lds(16B) staging, 16x16x32 MFMA. Q pre-scaled 0.125*log2e.
// Epilogue: per-mt 32x128 chunk via LDS, coalesced 32B stores.
// Q,K: [B,H,S,HD]; V transposed: [B,H,HD,S].
// ---------------------------------------------------------------------------
__global__ __launch_bounds__(256) void gemm_qkv(
    const ushort_t* __restrict__ X, const ushort_t* __restrict__ wt,
    const ushort_t* __restrict__ cB,
    ushort_t* __restrict__ Qb, ushort_t* __restrict__ Kb, ushort_t* __restrict__ Vtb) {
    const int z = blockIdx.z;
    const ushort_t* Wt = wt + (size_t)z * Dd * Dd;
    const ushort_t* bias = cB + z * 1024;

    __shared__ __align__(16) ushort_t smem[2][2][128 * 32];  // 32 KB

    const int tid = threadIdx.x;
    const int lane = tid & 63, wv = tid >> 6;
    const int quad = lane >> 4, l15 = lane & 15;
    const int wrow = (wv >> 1) * 64, wcol = (wv & 1) * 64;
    // T1 XCD swizzle (bijective: 256 tiles per z, 256%8==0)
    const int lin = blockIdx.y * 8 + blockIdx.x;
    const int swz = (lin & 7) * 32 + (lin >> 3);
    const int row0 = (swz >> 3) * 128, col0 = (swz & 7) * 128;
    const int lrow = lane >> 2, lcol = (lane & 3) * 8;

    const f32x4 fzero = {0.f, 0.f, 0.f, 0.f};
    f32x4 acc[4][4];
    for (int mt = 0; mt < 4; mt++)
        for (int nt = 0; nt < 4; nt++) acc[mt][nt] = fzero;

    for (int j = 0; j < 2; j++) {
        int ch = wv * 2 + j;
        gload_lds16(&X[(size_t)(row0 + ch * 16 + lrow) * Dd + lcol],
                    &smem[0][0][ch * 512]);
        gload_lds16(&Wt[(size_t)(col0 + ch * 16 + lrow) * Dd + lcol],
                    &smem[0][1][ch * 512]);
    }

    for (int k0 = 0; k0 < Dd; k0 += 32) {
        const int buf = (k0 >> 5) & 1;
        __syncthreads();
        if (k0 + 32 < Dd) {
            for (int j = 0; j < 2; j++) {
                int ch = wv * 2 + j;
                gload_lds16(&X[(size_t)(row0 + ch * 16 + lrow) * Dd + k0 + 32 + lcol],
                            &smem[buf ^ 1][0][ch * 512]);
                gload_lds16(&Wt[(size_t)(col0 + ch * 16 + lrow) * Dd + k0 + 32 + lcol],
                            &smem[buf ^ 1][1][ch * 512]);
            }
        }
        const ushort_t* As = &smem[buf][0][0];
        const ushort_t* Bs = &smem[buf][1][0];
        bf16x8 af[4], bfr[4];
        for (int mt = 0; mt < 4; mt++)
            af[mt] = *(const bf16x8*)(&As[(wrow + mt * 16 + l15) * 32 + quad * 8]);
        for (int nt = 0; nt < 4; nt++)
            bfr[nt] = *(const bf16x8*)(&Bs[(wcol + nt * 16 + l15) * 32 + quad * 8]);
        for (int mt = 0; mt < 4; mt++)
            for (int nt = 0; nt < 4; nt++)
                acc[mt][nt] = __builtin_amdgcn_mfma_f32_16x16x32_bf16(
                    af[mt], bfr[nt], acc[mt][nt], 0, 0, 0);
    }

    // ---- epilogue: per-mt 32x128 chunk via LDS, coalesced 32B stores ----
    const float qscale = 0.18033688f;  // 0.125 * log2(e)
    ushort_t* Cs = &smem[0][0][0];
    for (int mt = 0; mt < 4; mt++) {
        __syncthreads();
        for (int nt = 0; nt < 4; nt++) {
            int gn = col0 + wcol + nt * 16 + l15;
            float bv_ = bf2f(bias[gn]);
            for (int r = 0; r < 4; r++) {
                float v = acc[mt][nt][r] + bv_;
                if (z == 0) v *= qscale;
                int ric = (wv >> 1) * 16 + quad * 4 + r;
                Cs[ric * 136 + wcol + nt * 16 + l15] = f2bf(v);
            }
        }
        __syncthreads();
        if (z == 2) {
            int c = tid >> 1, r0 = (tid & 1) * 16;
            int gn = col0 + c, h = gn >> 6, d = gn & 63;
            int gmbase = row0 + (r0 >> 4) * 64 + mt * 16;
            int b = gmbase >> 11, s0 = gmbase & 2047;
            union { ushort_t u[16]; uint4 q[2]; } pk;
            for (int i = 0; i < 16; i++) pk.u[i] = Cs[(r0 + i) * 136 + c];
            uint4* dst = (uint4*)&Vtb[((size_t)((b * Hh + h) * HD + d)) * Ss + s0];
            dst[0] = pk.q[0];
            dst[1] = pk.q[1];
        } else {
            int ric = tid >> 3, c0 = (tid & 7) * 16;
            int gm = row0 + (ric >> 4) * 64 + mt * 16 + (ric & 15);
            int gn = col0 + c0, h = gn >> 6, d0 = gn & 63;
            int b = gm >> 11, s = gm & 2047;
            const uint4* src = (const uint4*)&Cs[ric * 136 + c0];
            ushort_t* Ob = (z == 0) ? Qb : Kb;
            uint4* dst = (uint4*)&Ob[((size_t)((b * Hh + h) * Ss + s)) * HD + d0];
            dst[0] = src[0];
            dst[1] = src[1];
        }
    }
}

// ---------------------------------------------------------------------------
// Kernel 2: flash attention — R4 (best measured: 47.7us; six orthogonal
// levers R2/R3/R5/R6/R7/R8 all null/regressed around this point).
// 2-deep score pipeline: QK(t) MFMAs interleaved with exp2(t-1); PV(t-1)
// from register V-frags; 4 waves, 128q/block, 40KB LDS, grid (32,16).
// Same-bh blocks already co-locate per XCD (lin%8 == bh%8; 4 heads x 512KB
// = 2MB/XCD L2) — no swizzle needed.
// C-layout 32x32: col=lane&31, row=(reg&3)+8*(reg>>2)+4*(lane>>5).
// ---------------------------------------------------------------------------
#define ATTN_ITER(T, PREV, CUR, DOPV, DOSTAGE)                                \
  {                                                                           \
    const int t_ = (T);                                                       \
    const int kb_ = t_ * 64;                                                  \
    const int bufc_ = t_ & 1;                                                 \
    __syncthreads();                                                          \
    if (DOSTAGE) {                                                            \
      _Pragma("unroll")                                                       \
      for (int j = 0; j < 2; j++) {                                           \
        int row = wv * 16 + j * 8;                                            \
        gload_lds16(&Kh[(size_t)(kb_ + 64 + row + r8) * HD + gc * 8],         \
                    &Ks[bufc_ ^ 1][row * 64]);                                \
        gload_lds16(&Vh[(size_t)(row + r8) * Ss + kb_ + 64 + gc * 8],         \
                    &Vs[bufc_ ^ 1][row * 64]);                                \
      }                                                                       \
    }                                                                         \
    const ushort_t* ks_ = &Ks[bufc_][0];                                      \
    const ushort_t* vs_ = &Vs[bufc_][0];                                      \
    _Pragma("unroll")                                                         \
    for (int mt = 0; mt < 2; mt++) {                                          \
      _Pragma("unroll")                                                       \
      for (int r4 = 0; r4 < 4; r4++) {                                        \
        f32x4 mk = *(const f32x4*)(&maskF[kb_ + mt * 32 + r4 * 8 + hi * 4]);  \
        CUR[mt][r4 * 4 + 0] = mk[0];                                          \
        CUR[mt][r4 * 4 + 1] = mk[1];                                          \
        CUR[mt][r4 * 4 + 2] = mk[2];                                          \
        CUR[mt][r4 * 4 + 3] = mk[3];                                          \
      }                                                                       \
    }                                                                         \
    __builtin_amdgcn_s_setprio(1);                                            \
    _Pragma("unroll")                                                         \
    for (int u = 0; u < 8; u++) {                                             \
      const int ksp_ = u >> 1, mt_ = u & 1;                                   \
      bf16x8 kf = *(const bf16x8*)(                                           \
          &ks_[(mt_ * 32 + n) * 64 + ((ksp_ * 2 + hi) ^ sw) * 8]);            \
      CUR[mt_] = __builtin_amdgcn_mfma_f32_32x32x16_bf16(                     \
          kf, qf[ksp_], CUR[mt_], 0, 0, 0);                                   \
      if (DOPV) {                                                             \
        PREV[0][u * 2 + 0] = EXP2(PREV[0][u * 2 + 0]);                        \
        PREV[0][u * 2 + 1] = EXP2(PREV[0][u * 2 + 1]);                        \
        PREV[1][u * 2 + 0] = EXP2(PREV[1][u * 2 + 0]);                        \
        PREV[1][u * 2 + 1] = EXP2(PREV[1][u * 2 + 1]);                        \
      }                                                                       \
    }                                                                         \
    __builtin_amdgcn_s_setprio(0);                                            \
    if (DOPV) {                                                               \
      _Pragma("unroll")                                                       \
      for (int c = 0; c < 4; c++) {                                           \
        const int mt_ = c >> 1, cc_ = (c & 1) * 8;                            \
        uint32_t a0 = cvtpk_bf16(PREV[mt_][cc_ + 0], PREV[mt_][cc_ + 1]);     \
        uint32_t a1 = cvtpk_bf16(PREV[mt_][cc_ + 2], PREV[mt_][cc_ + 3]);     \
        uint32_t b0 = cvtpk_bf16(PREV[mt_][cc_ + 4], PREV[mt_][cc_ + 5]);     \
        uint32_t b1 = cvtpk_bf16(PREV[mt_][cc_ + 6], PREV[mt_][cc_ + 7]);     \
        asm("v_permlane32_swap_b32 %0, %1" : "+v"(a0), "+v"(b0));             \
        asm("v_permlane32_swap_b32 %0, %1" : "+v"(a1), "+v"(b1));             \
        union { uint32_t w[4]; bf16x8 v; } pa;                                \
        pa.w[0] = a0; pa.w[1] = a1; pa.w[2] = b0; pa.w[3] = b1;               \
        __builtin_amdgcn_s_setprio(1);                                        \
        _Pragma("unroll")                                                     \
        for (int dt = 0; dt < 2; dt++)                                        \
          o[dt] = __builtin_amdgcn_mfma_f32_32x32x16_bf16(                    \
              pa.v, vfr[c * 2 + dt], o[dt], 0, 0, 0);                         \
        o_l = __builtin_amdgcn_mfma_f32_32x32x16_bf16(                        \
            pa.v, onesf, o_l, 0, 0, 0);                                       \
        __builtin_amdgcn_s_setprio(0);                                        \
      }                                                                       \
    }                                                                         \
    _Pragma("unroll")                                                         \
    for (int c = 0; c < 4; c++) {                                             \
      _Pragma("unroll")                                                       \
      for (int dt = 0; dt < 2; dt++)                                          \
        vfr[c * 2 + dt] = *(const bf16x8*)(                                   \
            &vs_[(dt * 32 + n) * 64 + ((c * 2 + hi) ^ sw) * 8]);              \
    }                                                                         \
  }

__global__ __launch_bounds__(256, 2) void attn(
    const ushort_t* __restrict__ Q, const ushort_t* __restrict__ K,
    const ushort_t* __restrict__ Vt, const ushort_t* __restrict__ mask,
    ushort_t* __restrict__ ctx) {
    const int tid = threadIdx.x;
    const int lane = tid & 63, wv = tid >> 6;
    const int n = lane & 31, hi = lane >> 5;
    const int bh = blockIdx.x;
    const int b = bh >> 4, h = bh & 15;
    const int q0 = blockIdx.y * 128 + wv * 32;

    const ushort_t* Qh = Q + (size_t)bh * Ss * HD;
    const ushort_t* Kh = K + (size_t)bh * Ss * HD;
    const ushort_t* Vh = Vt + (size_t)bh * HD * Ss;

    __shared__ __align__(16) ushort_t Ks[2][64 * 64];  // 16KB
    __shared__ __align__(16) ushort_t Vs[2][64 * 64];  // 16KB
    __shared__ __align__(16) float maskF[Ss];          // 8KB: (m-4)*log2e

    for (int i = tid; i < Ss; i += 256)
        maskF[i] = (bf2f(mask[b * Ss + i]) - 4.0f) * 1.4426950f;

    const int r8 = lane >> 3, c8 = lane & 7, gc = c8 ^ r8;  // XOR swizzle
    const int sw = n & 7;  // == row&7 for rows = tile*32 + n

    // stage kb=0 (wave wv: K rows wv*16..+16, V (d-)rows wv*16..+16)
    for (int j = 0; j < 2; j++) {
        int row = wv * 16 + j * 8;
        gload_lds16(&Kh[(size_t)(row + r8) * HD + gc * 8], &Ks[0][row * 64]);
        gload_lds16(&Vh[(size_t)(row + r8) * Ss + gc * 8], &Vs[0][row * 64]);
    }

    // Q fragments (B-frag lane(hi,n)): Q[q0 + n][ks*16 + hi*8 + 0..8)
    bf16x8 qf[4];
#pragma unroll
    for (int ks = 0; ks < 4; ks++)
        qf[ks] = *(const bf16x8*)(&Qh[(size_t)(q0 + n) * HD + ks * 16 + hi * 8]);

    bf16x8 onesf;
    {
        union { ushort_t u[8]; bf16x8 v; } ou;
        for (int i = 0; i < 8; i++) ou.u[i] = 0x3F80;  // bf16 1.0
        onesf = ou.v;
    }

    f32x16 o[2], o_l;
#pragma unroll
    for (int r = 0; r < 16; r++) { o[0][r] = 0.f; o[1][r] = 0.f; o_l[r] = 0.f; }

    f32x16 stA[2], stB[2];
    bf16x8 vfr[8];

    // t=0: QK -> stA, vfr = V(0). tiles (1,2)..(29,30): pipelined pairs.
    ATTN_ITER(0, stB, stA, 0, 1)
    for (int it2 = 0; it2 < 15; it2++) {
        ATTN_ITER(2 * it2 + 1, stA, stB, 1, 1)
        ATTN_ITER(2 * it2 + 2, stB, stA, 1, 1)
    }
    ATTN_ITER(31, stA, stB, 1, 0)

    // ---- epilogue: finish tile 31 (exp + cvt + PV), normalize, store ----
#pragma unroll
    for (int mt = 0; mt < 2; mt++)
#pragma unroll
        for (int r = 0; r < 16; r++) stB[mt][r] = EXP2(stB[mt][r]);
#pragma unroll
    for (int c = 0; c < 4; c++) {
        const int mt = c >> 1, cc = (c & 1) * 8;
        uint32_t a0 = cvtpk_bf16(stB[mt][cc + 0], stB[mt][cc + 1]);
        uint32_t a1 = cvtpk_bf16(stB[mt][cc + 2], stB[mt][cc + 3]);
        uint32_t b0 = cvtpk_bf16(stB[mt][cc + 4], stB[mt][cc + 5]);
        uint32_t b1 = cvtpk_bf16(stB[mt][cc + 6], stB[mt][cc + 7]);
        asm("v_permlane32_swap_b32 %0, %1" : "+v"(a0), "+v"(b0));
        asm("v_permlane32_swap_b32 %0, %1" : "+v"(a1), "+v"(b1));
        union { uint32_t w[4]; bf16x8 v; } pa;
        pa.w[0] = a0; pa.w[1] = a1; pa.w[2] = b0; pa.w[3] = b1;
#pragma unroll
        for (int dt = 0; dt < 2; dt++)
            o[dt] = __builtin_amdgcn_mfma_f32_32x32x16_bf16(
                pa.v, vfr[c * 2 + dt], o[dt], 0, 0, 0);
        o_l = __builtin_amdgcn_mfma_f32_32x32x16_bf16(pa.v, onesf, o_l, 0, 0, 0);
    }

#pragma unroll
    for (int r = 0; r < 16; r++) {
        int q = q0 + (r & 3) + 8 * (r >> 2) + 4 * hi;
        float linv = 1.f / o_l[r];
#pragma unroll
        for (int dt = 0; dt < 2; dt++) {
            ctx[((size_t)(b * Ss + q)) * Dd + h * HD + dt * 32 + n] =
                f2bf(o[dt][r] * linv);
        }
    }
}

// ---------------------------------------------------------------------------
// Kernel 3: output projection + bias + residual -> bf16 x buffer.
// R12: 128x128 tiles (gemm_qkv-verified main loop: 16 MFMA per 8
// ds_read_b128 vs old 8-per-6; staging instrs per MFMA halve) + T1 XCD
// swizzle (nwg=256, bijective). grid=(8,32)=256 blocks, 4 waves.
// Epilogue: same direct-store pattern as before (per-element bias+residual).
// ---------------------------------------------------------------------------
__global__ __launch_bounds__(256) void gemm_out(
    const ushort_t* __restrict__ A, const ushort_t* __restrict__ Wt,
    const ushort_t* __restrict__ bo, const ushort_t* __restrict__ X,
    ushort_t* __restrict__ xout) {
    __shared__ __align__(16) ushort_t smem[2][2][128 * 32];  // 32 KB

    const int tid = threadIdx.x;
    const int lane = tid & 63, wv = tid >> 6;
    const int quad = lane >> 4, l15 = lane & 15;
    const int wrow = (wv >> 1) * 64, wcol = (wv & 1) * 64;
    // T1 XCD swizzle (bijective: 256 tiles, 256%8==0)
    const int lin = blockIdx.y * 8 + blockIdx.x;
    const int swz = (lin & 7) * 32 + (lin >> 3);
    const int row0 = (swz >> 3) * 128, col0 = (swz & 7) * 128;
    const int lrow = lane >> 2, lcol = (lane & 3) * 8;

    const f32x4 fzero = {0.f, 0.f, 0.f, 0.f};
    f32x4 acc[4][4];
    for (int mt = 0; mt < 4; mt++)
        for (int nt = 0; nt < 4; nt++) acc[mt][nt] = fzero;

    for (int j = 0; j < 2; j++) {
        int ch = wv * 2 + j;
        gload_lds16(&A[(size_t)(row0 + ch * 16 + lrow) * Dd + lcol],
                    &smem[0][0][ch * 512]);
        gload_lds16(&Wt[(size_t)(col0 + ch * 16 + lrow) * Dd + lcol],
                    &smem[0][1][ch * 512]);
    }

    for (int k0 = 0; k0 < Dd; k0 += 32) {
        const int buf = (k0 >> 5) & 1;
        __syncthreads();
        if (k0 + 32 < Dd) {
            for (int j = 0; j < 2; j++) {
                int ch = wv * 2 + j;
                gload_lds16(&A[(size_t)(row0 + ch * 16 + lrow) * Dd + k0 + 32 + lcol],
                            &smem[buf ^ 1][0][ch * 512]);
                gload_lds16(&Wt[(size_t)(col0 + ch * 16 + lrow) * Dd + k0 + 32 + lcol],
                            &smem[buf ^ 1][1][ch * 512]);
            }
        }
        const ushort_t* As = &smem[buf][0][0];
        const ushort_t* Bs = &smem[buf][1][0];
        bf16x8 af[4], bfr[4];
        for (int mt = 0; mt < 4; mt++)
            af[mt] = *(const bf16x8*)(&As[(wrow + mt * 16 + l15) * 32 + quad * 8]);
        for (int nt = 0; nt < 4; nt++)
            bfr[nt] = *(const bf16x8*)(&Bs[(wcol + nt * 16 + l15) * 32 + quad * 8]);
        for (int mt = 0; mt < 4; mt++)
            for (int nt = 0; nt < 4; nt++)
                acc[mt][nt] = __builtin_amdgcn_mfma_f32_16x16x32_bf16(
                    af[mt], bfr[nt], acc[mt][nt], 0, 0, 0);
    }

    for (int mt = 0; mt < 4; mt++)
        for (int nt = 0; nt < 4; nt++)
            for (int r = 0; r < 4; r++) {
                int gm = row0 + wrow + mt * 16 + quad * 4 + r;
                int gn = col0 + wcol + nt * 16 + l15;
                float v = acc[mt][nt][r] + bf2f(bo[gn]) + bf2f(X[(size_t)gm * Dd + gn]);
                xout[(size_t)gm * Dd + gn] = f2bf(v);
            }
}

// ---------------------------------------------------------------------------
// Kernel 4: LayerNorm over rows of x (bf16) -> out (dtype per flag).
// ---------------------------------------------------------------------------
__global__ __launch_bounds__(256) void ln_k(
    const ushort_t* __restrict__ x, const ushort_t* __restrict__ gamma,
    const ushort_t* __restrict__ beta, const int* __restrict__ flag,
    void* __restrict__ out) {
    const int row = blockIdx.x;
    const int tid = threadIdx.x;
    const int f = *flag;

    union { uint2 q; ushort_t u[4]; } xv;
    xv.q = ((const uint2*)(x + (size_t)row * Dd))[tid];
    float xi[4];
    for (int i = 0; i < 4; i++) xi[i] = bf2f(xv.u[i]);
    float s = (xi[0] + xi[1]) + (xi[2] + xi[3]);
    float ss = (xi[0] * xi[0] + xi[1] * xi[1]) + (xi[2] * xi[2] + xi[3] * xi[3]);
    for (int off = 1; off < 64; off <<= 1) {
        s += __shfl_xor(s, off);
        ss += __shfl_xor(ss, off);
    }
    __shared__ float ps[4], pss[4];
    int wv = tid >> 6;
    if ((tid & 63) == 0) { ps[wv] = s; pss[wv] = ss; }
    __syncthreads();
    s = ps[0] + ps[1] + ps[2] + ps[3];
    ss = pss[0] + pss[1] + pss[2] + pss[3];
    float mu = s * (1.f / Dd);
    float var = ss * (1.f / Dd) - mu * mu;
    float rstd = rsqrtf(fmaxf(var, 0.f) + 1e-12f);

    const int c0 = tid * 4;
    float r[4];
    for (int i = 0; i < 4; i++) {
        float g = bf2f(gamma[c0 + i]);
        float bb = bf2f(beta[c0 + i]);
        r[i] = (xi[i] - mu) * rstd * g + bb;
    }
    if (f) {
        float4 o4 = {r[0], r[1], r[2], r[3]};
        ((float4*)out)[(size_t)row * 256 + tid] = o4;
    } else {
        union { ushort_t u[4]; uint2 q; } pk;
        for (int i = 0; i < 4; i++) pk.u[i] = f2bf(r[i]);
        *(uint2*)((ushort_t*)out + (size_t)row * Dd + c0) = pk.q;
    }
}

// ---------------------------------------------------------------------------
extern "C" void kernel_launch(void* const* d_in, const int* in_sizes, int n_in,
                              void* d_out, int out_size, void* d_ws, size_t ws_size,
                              hipStream_t stream) {
    char* ws = (char*)d_ws;
    int* flag       = (int*)ws;                          // @0
    ushort_t* cMask = (ushort_t*)(ws + (64ull << 10));   // @64KB  (8KB)
    ushort_t* cB    = (ushort_t*)(ws + (96ull << 10));   // @96KB  (12KB)
    ushort_t* cX    = (ushort_t*)(ws + (1ull << 20));    // @1MB   (8MB)
    ushort_t* wt    = (ushort_t*)(ws + (17ull << 20));   // @17MB  (8MB)
    ushort_t* Qb    = (ushort_t*)(ws + (25ull << 20));   // @25MB  (8MB)
    ushort_t* Kb    = (ushort_t*)(ws + (33ull << 20));   // @33MB  (8MB)
    ushort_t* Vtb   = (ushort_t*)(ws + (41ull << 20));   // @41MB  (8MB)
    ushort_t* ctx   = (ushort_t*)(ws + (49ull << 20));   // @49MB  (8MB)
    ushort_t* xbuf  = (ushort_t*)(ws + (25ull << 20));   // reuse Qb (8MB bf16)

    hipLaunchKernelGGL(prep_k, dim3(2048), dim3(256), 0, stream,
                       d_in[0], d_in[1], d_in[3], d_in[5], d_in[7], d_in[9],
                       d_in[10], d_in[11], d_in[2], d_in[4], d_in[6], d_in[8],
                       flag, cX, cMask, cB, wt);
    hipLaunchKernelGGL(gemm_qkv, dim3(8, 32, 3), dim3(256), 0, stream,
                       cX, wt, cB, Qb, Kb, Vtb);
    hipLaunchKernelGGL(attn, dim3(32, 16), dim3(256), 0, stream,
                       Qb, Kb, Vtb, cMask, ctx);
    hipLaunchKernelGGL(gemm_out, dim3(8, 32), dim3(256), 0, stream,
                       ctx, wt + 3ull * Dd * Dd, cB + 3 * 1024, cX, xbuf);
    hipLaunchKernelGGL(ln_k, dim3(Mtot), dim3(256), 0, stream,
                       xbuf, cB + 4 * 1024, cB + 5 * 1024, flag, d_out);
}

// Round 13
// 202.816 us; speedup vs baseline: 1.0241x; 1.0241x over previous
//
#include <hip/hip_runtime.h>
#include <stdint.h>

// Problem: B=2, S=2048, D=1024, H=16, HD=64.
// Reference dtype fp32; harness may deliver fp32 OR bf16. Runtime-detected.
#define Bb 2
#define Ss 2048
#define Dd 1024
#define Hh 16
#define HD 64
#define Mtot 4096  // B*S

typedef __bf16 bf16x8 __attribute__((ext_vector_type(8)));
typedef float f32x4 __attribute__((ext_vector_type(4)));
typedef float f32x16 __attribute__((ext_vector_type(16)));
typedef unsigned short ushort_t;

#if __has_builtin(__builtin_amdgcn_exp2f)
#define EXP2(x) __builtin_amdgcn_exp2f(x)   // single v_exp_f32
#else
#define EXP2(x) __expf((x) * 0.6931472f)
#endif

__device__ __forceinline__ float bf2f(ushort_t u) {
    union { uint32_t i; float f; } v;
    v.i = ((uint32_t)u) << 16;
    return v.f;
}

__device__ __forceinline__ ushort_t f2bf(float f) {
    union { float f; uint32_t i; } v;
    v.f = f;
    uint32_t u = v.i;
    u += 0x7FFFu + ((u >> 16) & 1u);  // round-to-nearest-even
    return (ushort_t)(u >> 16);
}

// v_cvt_pk_bf16_f32: dst.lo16 = bf16(lo), dst.hi16 = bf16(hi), RNE.
__device__ __forceinline__ uint32_t cvtpk_bf16(float lo, float hi) {
    uint32_t r;
    asm("v_cvt_pk_bf16_f32 %0, %1, %2" : "=v"(r) : "v"(lo), "v"(hi));
    return r;
}

__device__ __forceinline__ float load_in(const void* p, size_t i, int isf32) {
    if (isf32) return ((const float*)p)[i];
    return bf2f(((const ushort_t*)p)[i]);
}

// async global->LDS, 16B per lane; LDS dest = wave-uniform base + lane*16 (HW)
__device__ __forceinline__ void gload_lds16(const void* g, void* l) {
    __builtin_amdgcn_global_load_lds(
        (const __attribute__((address_space(1))) void*)g,
        (__attribute__((address_space(3))) void*)l, 16, 0, 0);
}

// ---------------------------------------------------------------------------
// Kernel P: fused prep (R11-exact, best measured). Blocks 0..1023:
// vectorized convert of X/mask/biases. Blocks 1024..2047: vectorized 64x64
// transpose W -> wt (LDS pitch 72 + y-chunk XOR swizzle; uint4 loads/stores).
// ---------------------------------------------------------------------------
#define NVEC 525568ull  // 524288 (X) + 512 (mask) + 768 (6x1024 biases)
__global__ __launch_bounds__(256) void prep_k(
    const void* X, const void* mask, const void* bq, const void* bk,
    const void* bv, const void* bo, const void* g, const void* be,
    const void* Wq, const void* Wk, const void* Wv, const void* Wo,
    int* __restrict__ flag, ushort_t* __restrict__ cX,
    ushort_t* __restrict__ cMask, ushort_t* __restrict__ cB,
    ushort_t* __restrict__ wt) {
    __shared__ int sflag;
    __shared__ __align__(16) ushort_t ttile[64][72];  // 9216B, pitch 144B
    const int tid = threadIdx.x;
    {
        const int lane = tid & 63;
        if (tid < 64) {
            const ushort_t* Xu = (const ushort_t*)X;
            int local = 0;
            for (int i = lane; i < 2048; i += 64) {
                int e = (Xu[i] >> 7) & 0xFF;
                local += (e >= 0x90);
            }
            for (int off = 1; off < 64; off <<= 1) local += __shfl_xor(local, off);
            if (lane == 0) sflag = (local >= 4) ? 1 : 0;
        }
    }
    __syncthreads();
    const int f = sflag;
    if (blockIdx.x == 0 && tid == 0) *flag = f;

    if (blockIdx.x < 1024) {
        const size_t stride = 1024ull * 256ull;
        for (size_t t = (size_t)blockIdx.x * 256 + tid; t < NVEC; t += stride) {
            const void* src;
            ushort_t* dst;
            size_t v;
            if (t < 524288ull) {
                src = X; dst = cX; v = t;
            } else if (t < 524800ull) {
                src = mask; dst = cMask; v = t - 524288ull;
            } else {
                size_t j = t - 524800ull;        // 0..767, 128 vecs / segment
                int w = (int)(j >> 7);
                src = (w == 0) ? bq : (w == 1) ? bk : (w == 2) ? bv
                    : (w == 3) ? bo : (w == 4) ? g : be;
                dst = cB + w * 1024;
                v = j & 127;
            }
            if (f) {
                const float4* s4 = (const float4*)src;
                float4 a = s4[v * 2], b = s4[v * 2 + 1];
                union { ushort_t u[8]; uint4 q; } pk;
                pk.u[0] = f2bf(a.x); pk.u[1] = f2bf(a.y);
                pk.u[2] = f2bf(a.z); pk.u[3] = f2bf(a.w);
                pk.u[4] = f2bf(b.x); pk.u[5] = f2bf(b.y);
                pk.u[6] = f2bf(b.z); pk.u[7] = f2bf(b.w);
                ((uint4*)dst)[v] = pk.q;
            } else {
                ((uint4*)dst)[v] = ((const uint4*)src)[v];
            }
        }
    } else {
        // ---- vectorized 64x64 transpose: T[n][k] = W[k][n] ----
        int id2 = blockIdx.x - 1024;     // 0..1023
        int z = id2 >> 8;                // matrix 0..3
        int rem = id2 & 255;
        int bx = rem & 15, by = rem >> 4;  // col-tile, row-tile
        const void* W = (z == 0) ? Wq : (z == 1) ? Wk : (z == 2) ? Wv : Wo;
        ushort_t* T = wt + (size_t)z * Dd * Dd;
        const int y0 = by * 64;  // W row origin (k)
        const int x0 = bx * 64;  // W col origin (n)

        // write phase: thread t -> row r = t>>2, x-chunk cq = t&3 (16 elems)
        {
            const int r = tid >> 2, cq = tid & 3;
            const int cq2 = cq ^ ((r >> 4) & 3);  // y-chunk XOR swizzle
            union { ushort_t u[16]; uint4 q[2]; } pk;
            if (f) {
                const float* Wf = (const float*)W;
                const float4* src = (const float4*)&Wf[(size_t)(y0 + r) * Dd + x0 + cq * 16];
#pragma unroll
                for (int j = 0; j < 4; j++) {
                    float4 a = src[j];
                    pk.u[j * 4 + 0] = f2bf(a.x);
                    pk.u[j * 4 + 1] = f2bf(a.y);
                    pk.u[j * 4 + 2] = f2bf(a.z);
                    pk.u[j * 4 + 3] = f2bf(a.w);
                }
            } else {
                const ushort_t* Wu = (const ushort_t*)W;
                const uint4* src = (const uint4*)&Wu[(size_t)(y0 + r) * Dd + x0 + cq * 16];
                pk.q[0] = src[0];
                pk.q[1] = src[1];
            }
            *(uint4*)&ttile[r][cq2 * 16] = pk.q[0];
            *(uint4*)&ttile[r][cq2 * 16 + 8] = pk.q[1];
        }
        __syncthreads();
        // read phase: thread t -> output row x = t>>2 (n), y-chunk yq = t&3
        {
            const int x = tid >> 2, yq = tid & 3;
            const int xs = x ^ (yq << 4);  // same swizzle: (y>>4)&3 == yq here
            union { ushort_t u[16]; uint4 q[2]; } pk;
#pragma unroll
            for (int i = 0; i < 16; i++) pk.u[i] = ttile[yq * 16 + i][xs];
            uint4* dst = (uint4*)&T[(size_t)(x0 + x) * Dd + y0 + yq * 16];
            dst[0] = pk.q[0];
            dst[1] = pk.q[1];
        }
    }
}

// ---------------------------------------------------------------------------
// Kernel 1: fused QKV projection (R4-exact; R12's T1 swizzle reverted —
// m160: XCD swizzle costs ~2% when operands are L3-resident, which they
// are here). grid=(N/128, M/128, 3), block=256 (4 waves), double-buffered
// global_load_lds(16B) staging, 16x16x32 MFMA. Q pre-scaled 0.125*log2e.
// Epilogue: per-mt 32x128 chunk via LDS, coalesced 32B stores.
// Q,K: [B,H,S,HD]; V transposed: [B,H,HD,S].
// ---------------------------------------------------------------------------
__global__ __launch_bounds__(256) void gemm_qkv(
    const ushort_t* __restrict__ X, const ushort_t* __restrict__ wt,
    const ushort_t* __restrict__ cB,
    ushort_t* __restrict__ Qb, ushort_t* __restrict__ Kb, ushort_t* __restrict__ Vtb) {
    const int z = blockIdx.z;
    const ushort_t* Wt = wt + (size_t)z * Dd * Dd;
    const ushort_t* bias = cB + z * 1024;

    __shared__ __align__(16) ushort_t smem[2][2][128 * 32];  // 32 KB

    const int tid = threadIdx.x;
    const int lane = tid & 63, wv = tid >> 6;
    const int quad = lane >> 4, l15 = lane & 15;
    const int wrow = (wv >> 1) * 64, wcol = (wv & 1) * 64;
    const int row0 = blockIdx.y * 128, col0 = blockIdx.x * 128;
    const int lrow = lane >> 2, lcol = (lane & 3) * 8;

    const f32x4 fzero = {0.f, 0.f, 0.f, 0.f};
    f32x4 acc[4][4];
    for (int mt = 0; mt < 4; mt++)
        for (int nt = 0; nt < 4; nt++) acc[mt][nt] = fzero;

    for (int j = 0; j < 2; j++) {
        int ch = wv * 2 + j;
        gload_lds16(&X[(size_t)(row0 + ch * 16 + lrow) * Dd + lcol],
                    &smem[0][0][ch * 512]);
        gload_lds16(&Wt[(size_t)(col0 + ch * 16 + lrow) * Dd + lcol],
                    &smem[0][1][ch * 512]);
    }

    for (int k0 = 0; k0 < Dd; k0 += 32) {
        const int buf = (k0 >> 5) & 1;
        __syncthreads();
        if (k0 + 32 < Dd) {
            for (int j = 0; j < 2; j++) {
                int ch = wv * 2 + j;
                gload_lds16(&X[(size_t)(row0 + ch * 16 + lrow) * Dd + k0 + 32 + lcol],
                            &smem[buf ^ 1][0][ch * 512]);
                gload_lds16(&Wt[(size_t)(col0 + ch * 16 + lrow) * Dd + k0 + 32 + lcol],
                            &smem[buf ^ 1][1][ch * 512]);
            }
        }
        const ushort_t* As = &smem[buf][0][0];
        const ushort_t* Bs = &smem[buf][1][0];
        bf16x8 af[4], bfr[4];
        for (int mt = 0; mt < 4; mt++)
            af[mt] = *(const bf16x8*)(&As[(wrow + mt * 16 + l15) * 32 + quad * 8]);
        for (int nt = 0; nt < 4; nt++)
            bfr[nt] = *(const bf16x8*)(&Bs[(wcol + nt * 16 + l15) * 32 + quad * 8]);
        for (int mt = 0; mt < 4; mt++)
            for (int nt = 0; nt < 4; nt++)
                acc[mt][nt] = __builtin_amdgcn_mfma_f32_16x16x32_bf16(
                    af[mt], bfr[nt], acc[mt][nt], 0, 0, 0);
    }

    // ---- epilogue: per-mt 32x128 chunk via LDS, coalesced 32B stores ----
    const float qscale = 0.18033688f;  // 0.125 * log2(e)
    ushort_t* Cs = &smem[0][0][0];
    for (int mt = 0; mt < 4; mt++) {
        __syncthreads();
        for (int nt = 0; nt < 4; nt++) {
            int gn = col0 + wcol + nt * 16 + l15;
            float bv_ = bf2f(bias[gn]);
            for (int r = 0; r < 4; r++) {
                float v = acc[mt][nt][r] + bv_;
                if (z == 0) v *= qscale;
                int ric = (wv >> 1) * 16 + quad * 4 + r;
                Cs[ric * 136 + wcol + nt * 16 + l15] = f2bf(v);
            }
        }
        __syncthreads();
        if (z == 2) {
            int c = tid >> 1, r0 = (tid & 1) * 16;
            int gn = col0 + c, h = gn >> 6, d = gn & 63;
            int gmbase = row0 + (r0 >> 4) * 64 + mt * 16;
            int b = gmbase >> 11, s0 = gmbase & 2047;
            union { ushort_t u[16]; uint4 q[2]; } pk;
            for (int i = 0; i < 16; i++) pk.u[i] = Cs[(r0 + i) * 136 + c];
            uint4* dst = (uint4*)&Vtb[((size_t)((b * Hh + h) * HD + d)) * Ss + s0];
            dst[0] = pk.q[0];
            dst[1] = pk.q[1];
        } else {
            int ric = tid >> 3, c0 = (tid & 7) * 16;
            int gm = row0 + (ric >> 4) * 64 + mt * 16 + (ric & 15);
            int gn = col0 + c0, h = gn >> 6, d0 = gn & 63;
            int b = gm >> 11, s = gm & 2047;
            const uint4* src = (const uint4*)&Cs[ric * 136 + c0];
            ushort_t* Ob = (z == 0) ? Qb : Kb;
            uint4* dst = (uint4*)&Ob[((size_t)((b * Hh + h) * Ss + s)) * HD + d0];
            dst[0] = src[0];
            dst[1] = src[1];
        }
    }
}

// ---------------------------------------------------------------------------
// Kernel 2: flash attention — R4 (best measured: 47.7us; six orthogonal
// levers R2/R3/R5/R6/R7/R8 all null/regressed around this point).
// 2-deep score pipeline: QK(t) MFMAs interleaved with exp2(t-1); PV(t-1)
// from register V-frags; 4 waves, 128q/block, 40KB LDS, grid (32,16).
// C-layout 32x32: col=lane&31, row=(reg&3)+8*(reg>>2)+4*(lane>>5).
// ---------------------------------------------------------------------------
#define ATTN_ITER(T, PREV, CUR, DOPV, DOSTAGE)                                \
  {                                                                           \
    const int t_ = (T);                                                       \
    const int kb_ = t_ * 64;                                                  \
    const int bufc_ = t_ & 1;                                                 \
    __syncthreads();                                                          \
    if (DOSTAGE) {                                                            \
      _Pragma("unroll")                                                       \
      for (int j = 0; j < 2; j++) {                                           \
        int row = wv * 16 + j * 8;                                            \
        gload_lds16(&Kh[(size_t)(kb_ + 64 + row + r8) * HD + gc * 8],         \
                    &Ks[bufc_ ^ 1][row * 64]);                                \
        gload_lds16(&Vh[(size_t)(row + r8) * Ss + kb_ + 64 + gc * 8],         \
                    &Vs[bufc_ ^ 1][row * 64]);                                \
      }                                                                       \
    }                                                                         \
    const ushort_t* ks_ = &Ks[bufc_][0];                                      \
    const ushort_t* vs_ = &Vs[bufc_][0];                                      \
    _Pragma("unroll")                                                         \
    for (int mt = 0; mt < 2; mt++) {                                          \
      _Pragma("unroll")                                                       \
      for (int r4 = 0; r4 < 4; r4++) {                                        \
        f32x4 mk = *(const f32x4*)(&maskF[kb_ + mt * 32 + r4 * 8 + hi * 4]);  \
        CUR[mt][r4 * 4 + 0] = mk[0];                                          \
        CUR[mt][r4 * 4 + 1] = mk[1];                                          \
        CUR[mt][r4 * 4 + 2] = mk[2];                                          \
        CUR[mt][r4 * 4 + 3] = mk[3];                                          \
      }                                                                       \
    }                                                                         \
    __builtin_amdgcn_s_setprio(1);                                            \
    _Pragma("unroll")                                                         \
    for (int u = 0; u < 8; u++) {                                             \
      const int ksp_ = u >> 1, mt_ = u & 1;                                   \
      bf16x8 kf = *(const bf16x8*)(                                           \
          &ks_[(mt_ * 32 + n) * 64 + ((ksp_ * 2 + hi) ^ sw) * 8]);            \
      CUR[mt_] = __builtin_amdgcn_mfma_f32_32x32x16_bf16(                     \
          kf, qf[ksp_], CUR[mt_], 0, 0, 0);                                   \
      if (DOPV) {                                                             \
        PREV[0][u * 2 + 0] = EXP2(PREV[0][u * 2 + 0]);                        \
        PREV[0][u * 2 + 1] = EXP2(PREV[0][u * 2 + 1]);                        \
        PREV[1][u * 2 + 0] = EXP2(PREV[1][u * 2 + 0]);                        \
        PREV[1][u * 2 + 1] = EXP2(PREV[1][u * 2 + 1]);                        \
      }                                                                       \
    }                                                                         \
    __builtin_amdgcn_s_setprio(0);                                            \
    if (DOPV) {                                                               \
      _Pragma("unroll")                                                       \
      for (int c = 0; c < 4; c++) {                                           \
        const int mt_ = c >> 1, cc_ = (c & 1) * 8;                            \
        uint32_t a0 = cvtpk_bf16(PREV[mt_][cc_ + 0], PREV[mt_][cc_ + 1]);     \
        uint32_t a1 = cvtpk_bf16(PREV[mt_][cc_ + 2], PREV[mt_][cc_ + 3]);     \
        uint32_t b0 = cvtpk_bf16(PREV[mt_][cc_ + 4], PREV[mt_][cc_ + 5]);     \
        uint32_t b1 = cvtpk_bf16(PREV[mt_][cc_ + 6], PREV[mt_][cc_ + 7]);     \
        asm("v_permlane32_swap_b32 %0, %1" : "+v"(a0), "+v"(b0));             \
        asm("v_permlane32_swap_b32 %0, %1" : "+v"(a1), "+v"(b1));             \
        union { uint32_t w[4]; bf16x8 v; } pa;                                \
        pa.w[0] = a0; pa.w[1] = a1; pa.w[2] = b0; pa.w[3] = b1;               \
        __builtin_amdgcn_s_setprio(1);                                        \
        _Pragma("unroll")                                                     \
        for (int dt = 0; dt < 2; dt++)                                        \
          o[dt] = __builtin_amdgcn_mfma_f32_32x32x16_bf16(                    \
              pa.v, vfr[c * 2 + dt], o[dt], 0, 0, 0);                         \
        o_l = __builtin_amdgcn_mfma_f32_32x32x16_bf16(                        \
            pa.v, onesf, o_l, 0, 0, 0);                                       \
        __builtin_amdgcn_s_setprio(0);                                        \
      }                                                                       \
    }                                                                         \
    _Pragma("unroll")                                                         \
    for (int c = 0; c < 4; c++) {                                             \
      _Pragma("unroll")                                                       \
      for (int dt = 0; dt < 2; dt++)                                          \
        vfr[c * 2 + dt] = *(const bf16x8*)(                                   \
            &vs_[(dt * 32 + n) * 64 + ((c * 2 + hi) ^ sw) * 8]);              \
    }                                                                         \
  }

__global__ __launch_bounds__(256, 2) void attn(
    const ushort_t* __restrict__ Q, const ushort_t* __restrict__ K,
    const ushort_t* __restrict__ Vt, const ushort_t* __restrict__ mask,
    ushort_t* __restrict__ ctx) {
    const int tid = threadIdx.x;
    const int lane = tid & 63, wv = tid >> 6;
    const int n = lane & 31, hi = lane >> 5;
    const int bh = blockIdx.x;
    const int b = bh >> 4, h = bh & 15;
    const int q0 = blockIdx.y * 128 + wv * 32;

    const ushort_t* Qh = Q + (size_t)bh * Ss * HD;
    const ushort_t* Kh = K + (size_t)bh * Ss * HD;
    const ushort_t* Vh = Vt + (size_t)bh * HD * Ss;

    __shared__ __align__(16) ushort_t Ks[2][64 * 64];  // 16KB
    __shared__ __align__(16) ushort_t Vs[2][64 * 64];  // 16KB
    __shared__ __align__(16) float maskF[Ss];          // 8KB: (m-4)*log2e

    for (int i = tid; i < Ss; i += 256)
        maskF[i] = (bf2f(mask[b * Ss + i]) - 4.0f) * 1.4426950f;

    const int r8 = lane >> 3, c8 = lane & 7, gc = c8 ^ r8;  // XOR swizzle
    const int sw = n & 7;  // == row&7 for rows = tile*32 + n

    // stage kb=0 (wave wv: K rows wv*16..+16, V (d-)rows wv*16..+16)
    for (int j = 0; j < 2; j++) {
        int row = wv * 16 + j * 8;
        gload_lds16(&Kh[(size_t)(row + r8) * HD + gc * 8], &Ks[0][row * 64]);
        gload_lds16(&Vh[(size_t)(row + r8) * Ss + gc * 8], &Vs[0][row * 64]);
    }

    // Q fragments (B-frag lane(hi,n)): Q[q0 + n][ks*16 + hi*8 + 0..8)
    bf16x8 qf[4];
#pragma unroll
    for (int ks = 0; ks < 4; ks++)
        qf[ks] = *(const bf16x8*)(&Qh[(size_t)(q0 + n) * HD + ks * 16 + hi * 8]);

    bf16x8 onesf;
    {
        union { ushort_t u[8]; bf16x8 v; } ou;
        for (int i = 0; i < 8; i++) ou.u[i] = 0x3F80;  // bf16 1.0
        onesf = ou.v;
    }

    f32x16 o[2], o_l;
#pragma unroll
    for (int r = 0; r < 16; r++) { o[0][r] = 0.f; o[1][r] = 0.f; o_l[r] = 0.f; }

    f32x16 stA[2], stB[2];
    bf16x8 vfr[8];

    // t=0: QK -> stA, vfr = V(0). tiles (1,2)..(29,30): pipelined pairs.
    ATTN_ITER(0, stB, stA, 0, 1)
    for (int it2 = 0; it2 < 15; it2++) {
        ATTN_ITER(2 * it2 + 1, stA, stB, 1, 1)
        ATTN_ITER(2 * it2 + 2, stB, stA, 1, 1)
    }
    ATTN_ITER(31, stA, stB, 1, 0)

    // ---- epilogue: finish tile 31 (exp + cvt + PV), normalize, store ----
#pragma unroll
    for (int mt = 0; mt < 2; mt++)
#pragma unroll
        for (int r = 0; r < 16; r++) stB[mt][r] = EXP2(stB[mt][r]);
#pragma unroll
    for (int c = 0; c < 4; c++) {
        const int mt = c >> 1, cc = (c & 1) * 8;
        uint32_t a0 = cvtpk_bf16(stB[mt][cc + 0], stB[mt][cc + 1]);
        uint32_t a1 = cvtpk_bf16(stB[mt][cc + 2], stB[mt][cc + 3]);
        uint32_t b0 = cvtpk_bf16(stB[mt][cc + 4], stB[mt][cc + 5]);
        uint32_t b1 = cvtpk_bf16(stB[mt][cc + 6], stB[mt][cc + 7]);
        asm("v_permlane32_swap_b32 %0, %1" : "+v"(a0), "+v"(b0));
        asm("v_permlane32_swap_b32 %0, %1" : "+v"(a1), "+v"(b1));
        union { uint32_t w[4]; bf16x8 v; } pa;
        pa.w[0] = a0; pa.w[1] = a1; pa.w[2] = b0; pa.w[3] = b1;
#pragma unroll
        for (int dt = 0; dt < 2; dt++)
            o[dt] = __builtin_amdgcn_mfma_f32_32x32x16_bf16(
                pa.v, vfr[c * 2 + dt], o[dt], 0, 0, 0);
        o_l = __builtin_amdgcn_mfma_f32_32x32x16_bf16(pa.v, onesf, o_l, 0, 0, 0);
    }

#pragma unroll
    for (int r = 0; r < 16; r++) {
        int q = q0 + (r & 3) + 8 * (r >> 2) + 4 * hi;
        float linv = 1.f / o_l[r];
#pragma unroll
        for (int dt = 0; dt < 2; dt++) {
            ctx[((size_t)(b * Ss + q)) * Dd + h * HD + dt * 32 + n] =
                f2bf(o[dt][r] * linv);
        }
    }
}

// ---------------------------------------------------------------------------
// Kernel 3: output projection + bias + residual -> bf16 x buffer.
// R11-exact: 64x128 tiles, grid=(8,64)=512 blocks; double-buffered staging.
// (R12's 128x128 + T1 variant regressed; reverted.)
// ---------------------------------------------------------------------------
__global__ __launch_bounds__(256) void gemm_out(
    const ushort_t* __restrict__ A, const ushort_t* __restrict__ Wt,
    const ushort_t* __restrict__ bo, const ushort_t* __restrict__ X,
    ushort_t* __restrict__ xout) {
    __shared__ __align__(16) ushort_t smem[2][6144];  // 24 KB

    const int tid = threadIdx.x;
    const int lane = tid & 63, wv = tid >> 6;
    const int quad = lane >> 4, l15 = lane & 15;
    const int wrow = (wv >> 1) * 32, wcol = (wv & 1) * 64;
    const int row0 = blockIdx.y * 64, col0 = blockIdx.x * 128;
    const int lrow = lane >> 2, lcol = (lane & 3) * 8;

    const f32x4 fzero = {0.f, 0.f, 0.f, 0.f};
    f32x4 acc[2][4];
    for (int mt = 0; mt < 2; mt++)
        for (int nt = 0; nt < 4; nt++) acc[mt][nt] = fzero;

    gload_lds16(&A[(size_t)(row0 + wv * 16 + lrow) * Dd + lcol], &smem[0][wv * 512]);
    for (int j = 0; j < 2; j++) {
        int ch = wv * 2 + j;
        gload_lds16(&Wt[(size_t)(col0 + ch * 16 + lrow) * Dd + lcol],
                    &smem[0][2048 + ch * 512]);
    }

    for (int k0 = 0; k0 < Dd; k0 += 32) {
        const int buf = (k0 >> 5) & 1;
        __syncthreads();
        if (k0 + 32 < Dd) {
            gload_lds16(&A[(size_t)(row0 + wv * 16 + lrow) * Dd + k0 + 32 + lcol],
                        &smem[buf ^ 1][wv * 512]);
            for (int j = 0; j < 2; j++) {
                int ch = wv * 2 + j;
                gload_lds16(&Wt[(size_t)(col0 + ch * 16 + lrow) * Dd + k0 + 32 + lcol],
                            &smem[buf ^ 1][2048 + ch * 512]);
            }
        }
        const ushort_t* As = &smem[buf][0];
        const ushort_t* Bs = &smem[buf][2048];
        bf16x8 af[2], bfr[4];
        for (int mt = 0; mt < 2; mt++)
            af[mt] = *(const bf16x8*)(&As[(wrow + mt * 16 + l15) * 32 + quad * 8]);
        for (int nt = 0; nt < 4; nt++)
            bfr[nt] = *(const bf16x8*)(&Bs[(wcol + nt * 16 + l15) * 32 + quad * 8]);
        for (int mt = 0; mt < 2; mt++)
            for (int nt = 0; nt < 4; nt++)
                acc[mt][nt] = __builtin_amdgcn_mfma_f32_16x16x32_bf16(
                    af[mt], bfr[nt], acc[mt][nt], 0, 0, 0);
    }

    for (int mt = 0; mt < 2; mt++)
        for (int nt = 0; nt < 4; nt++)
            for (int r = 0; r < 4; r++) {
                int gm = row0 + wrow + mt * 16 + quad * 4 + r;
                int gn = col0 + wcol + nt * 16 + l15;
                float v = acc[mt][nt][r] + bf2f(bo[gn]) + bf2f(X[(size_t)gm * Dd + gn]);
                xout[(size_t)gm * Dd + gn] = f2bf(v);
            }
}

// ---------------------------------------------------------------------------
// Kernel 4: LayerNorm over rows of x (bf16) -> out (dtype per flag).
// ---------------------------------------------------------------------------
__global__ __launch_bounds__(256) void ln_k(
    const ushort_t* __restrict__ x, const ushort_t* __restrict__ gamma,
    const ushort_t* __restrict__ beta, const int* __restrict__ flag,
    void* __restrict__ out) {
    const int row = blockIdx.x;
    const int tid = threadIdx.x;
    const int f = *flag;

    union { uint2 q; ushort_t u[4]; } xv;
    xv.q = ((const uint2*)(x + (size_t)row * Dd))[tid];
    float xi[4];
    for (int i = 0; i < 4; i++) xi[i] = bf2f(xv.u[i]);
    float s = (xi[0] + xi[1]) + (xi[2] + xi[3]);
    float ss = (xi[0] * xi[0] + xi[1] * xi[1]) + (xi[2] * xi[2] + xi[3] * xi[3]);
    for (int off = 1; off < 64; off <<= 1) {
        s += __shfl_xor(s, off);
        ss += __shfl_xor(ss, off);
    }
    __shared__ float ps[4], pss[4];
    int wv = tid >> 6;
    if ((tid & 63) == 0) { ps[wv] = s; pss[wv] = ss; }
    __syncthreads();
    s = ps[0] + ps[1] + ps[2] + ps[3];
    ss = pss[0] + pss[1] + pss[2] + pss[3];
    float mu = s * (1.f / Dd);
    float var = ss * (1.f / Dd) - mu * mu;
    float rstd = rsqrtf(fmaxf(var, 0.f) + 1e-12f);

    const int c0 = tid * 4;
    float r[4];
    for (int i = 0; i < 4; i++) {
        float g = bf2f(gamma[c0 + i]);
        float bb = bf2f(beta[c0 + i]);
        r[i] = (xi[i] - mu) * rstd * g + bb;
    }
    if (f) {
        float4 o4 = {r[0], r[1], r[2], r[3]};
        ((float4*)out)[(size_t)row * 256 + tid] = o4;
    } else {
        union { ushort_t u[4]; uint2 q; } pk;
        for (int i = 0; i < 4; i++) pk.u[i] = f2bf(r[i]);
        *(uint2*)((ushort_t*)out + (size_t)row * Dd + c0) = pk.q;
    }
}

// ---------------------------------------------------------------------------
extern "C" void kernel_launch(void* const* d_in, const int* in_sizes, int n_in,
                              void* d_out, int out_size, void* d_ws, size_t ws_size,
                              hipStream_t stream) {
    char* ws = (char*)d_ws;
    int* flag       = (int*)ws;                          // @0
    ushort_t* cMask = (ushort_t*)(ws + (64ull << 10));   // @64KB  (8KB)
    ushort_t* cB    = (ushort_t*)(ws + (96ull << 10));   // @96KB  (12KB)
    ushort_t* cX    = (ushort_t*)(ws + (1ull << 20));    // @1MB   (8MB)
    ushort_t* wt    = (ushort_t*)(ws + (17ull << 20));   // @17MB  (8MB)
    ushort_t* Qb    = (ushort_t*)(ws + (25ull << 20));   // @25MB  (8MB)
    ushort_t* Kb    = (ushort_t*)(ws + (33ull << 20));   // @33MB  (8MB)
    ushort_t* Vtb   = (ushort_t*)(ws + (41ull << 20));   // @41MB  (8MB)
    ushort_t* ctx   = (ushort_t*)(ws + (49ull << 20));   // @49MB  (8MB)
    ushort_t* xbuf  = (ushort_t*)(ws + (25ull << 20));   // reuse Qb (8MB bf16)

    hipLaunchKernelGGL(prep_k, dim3(2048), dim3(256), 0, stream,
                       d_in[0], d_in[1], d_in[3], d_in[5], d_in[7], d_in[9],
                       d_in[10], d_in[11], d_in[2], d_in[4], d_in[6], d_in[8],
                       flag, cX, cMask, cB, wt);
    hipLaunchKernelGGL(gemm_qkv, dim3(8, 32, 3), dim3(256), 0, stream,
                       cX, wt, cB, Qb, Kb, Vtb);
    hipLaunchKernelGGL(attn, dim3(32, 16), dim3(256), 0, stream,
                       Qb, Kb, Vtb, cMask, ctx);
    hipLaunchKernelGGL(gemm_out, dim3(8, 64), dim3(256), 0, stream,
                       ctx, wt + 3ull * Dd * Dd, cB + 3 * 1024, cX, xbuf);
    hipLaunchKernelGGL(ln_k, dim3(Mtot), dim3(256), 0, stream,
                       xbuf, cB + 4 * 1024, cB + 5 * 1024, flag, d_out);
}